// Round 1
// baseline (89.731 us; speedup 1.0000x reference)
//
#include <hip/hip_runtime.h>
#include <math.h>

#define NPX 8192        // 8*32*32 pixels
#define NPATCH 8192
#define KK 27
#define REC 32          // patch record: 27 scaled + B2 + 3 centers + pad
#define XREC 28         // pixel record: 27 + pad
#define SPLITS 64
#define CHUNK (NPATCH / SPLITS)   // 128 patches per split
#define PXT 512                   // pixels per main block (256 thr x 2)
#define TILES (NPX / PXT)         // 16

__device__ __forceinline__ float fexp2(float x) {
#if __has_builtin(__builtin_amdgcn_exp2f)
    return __builtin_amdgcn_exp2f(x);
#else
    return exp2f(x);
#endif
}

// component k (0..27) of a float4 array, k must be compile-time constant after unroll
#define COMP(V, k) ((((k) & 3) == 0) ? V[(k) >> 2].x : (((k) & 3) == 1) ? V[(k) >> 2].y : (((k) & 3) == 2) ? V[(k) >> 2].z : V[(k) >> 2].w)

// ---------------- prep: scale patches, compute B2 + centers ----------------
__global__ void prep_patches(const float* __restrict__ patches,
                             const float* __restrict__ t,
                             float* __restrict__ rec) {
    int p = blockIdx.x * blockDim.x + threadIdx.x;
    if (p >= NPATCH) return;
    float bt2 = t[0];
    float at = sqrtf(1.0f - bt2);
    const float L2E = 1.4426950408889634f;
    float A2 = at * L2E / bt2;                 // logit slope in log2 units
    const float* src = patches + p * KK;
    float v[KK];
    float pn = 0.0f;
#pragma unroll
    for (int k = 0; k < KK; k++) { v[k] = src[k]; pn += v[k] * v[k]; }
    float B2 = -at * at * pn * L2E / (2.0f * bt2);
    float* r = rec + p * REC;
#pragma unroll
    for (int k = 0; k < KK; k++) r[k] = A2 * v[k];
    r[27] = B2;
    r[28] = v[4];    // center c=0 (k = 0*9+4)
    r[29] = v[13];   // center c=1
    r[30] = v[22];   // center c=2
    r[31] = 0.0f;
}

// ---------------- im2col: padded 3x3x3 neighborhood per pixel ----------------
__global__ void im2col(const float* __restrict__ x, float* __restrict__ xcol) {
    int idx = blockIdx.x * blockDim.x + threadIdx.x;   // px*28 + k
    if (idx >= NPX * XREC) return;
    int px = idx / XREC;
    int k = idx - px * XREC;
    float val = 0.0f;
    if (k < KK) {
        int b = px >> 10, rem = px & 1023, h = rem >> 5, w = rem & 31;
        int c = k / 9, r9 = k - c * 9;
        int dr = r9 / 3, dc = r9 - dr * 3;
        int hh = h + dr - 1, ww = w + dc - 1;
        if ((unsigned)hh < 32u && (unsigned)ww < 32u)
            val = x[b * 3072 + c * 1024 + hh * 32 + ww];
    }
    xcol[idx] = val;
}

// ---------------- main: fused dot + online softmax + center accumulation ----
__global__ void __launch_bounds__(256)
main_kernel(const float* __restrict__ rec, const float* __restrict__ xcol,
            float* __restrict__ pm, float* __restrict__ ps,
            float* __restrict__ pc0, float* __restrict__ pc1,
            float* __restrict__ pc2) {
    __shared__ float4 sP[CHUNK * 8];   // 16 KB
    const int split = blockIdx.x;      // 0..SPLITS-1
    const int tile = blockIdx.y;       // 0..TILES-1
    const int tid = threadIdx.x;

    // stage this split's patch records into LDS (coalesced float4)
    const float4* grec = (const float4*)rec + split * CHUNK * 8;
    for (int i = tid; i < CHUNK * 8; i += 256) sP[i] = grec[i];

    // two pixels per thread, neighborhoods in registers
    const int px0 = tile * PXT + tid;
    const int px1 = px0 + 256;
    float4 xa[7], xb[7];
    const float4* xc0 = (const float4*)(xcol + px0 * XREC);
    const float4* xc1 = (const float4*)(xcol + px1 * XREC);
#pragma unroll
    for (int i = 0; i < 7; i++) { xa[i] = xc0[i]; xb[i] = xc1[i]; }
    __syncthreads();

    float m0 = -1e30f, s0 = 0.0f, a00 = 0.0f, a01 = 0.0f, a02 = 0.0f;
    float m1 = -1e30f, s1 = 0.0f, a10 = 0.0f, a11 = 0.0f, a12 = 0.0f;

    for (int j = 0; j < CHUNK; j++) {
        const float4* r = &sP[j * 8];
        float4 g[8];
#pragma unroll
        for (int i = 0; i < 8; i++) g[i] = r[i];   // broadcast LDS reads
        float d0 = g[6].w;   // B2
        float d1 = g[6].w;
#pragma unroll
        for (int k = 0; k < KK; k++) {
            float pv = COMP(g, k);
            d0 = fmaf(COMP(xa, k), pv, d0);
            d1 = fmaf(COMP(xb, k), pv, d1);
        }
        // online softmax in log2 units, defer-max (threshold 8)
        bool cA = d0 > m0 + 8.0f;
        bool cB = d1 > m1 + 8.0f;
        if (__any(cA || cB)) {
            float m0n = fmaxf(m0, d0), m1n = fmaxf(m1, d1);
            float al0 = fexp2(m0 - m0n), al1 = fexp2(m1 - m1n);
            s0 *= al0; a00 *= al0; a01 *= al0; a02 *= al0; m0 = m0n;
            s1 *= al1; a10 *= al1; a11 *= al1; a12 *= al1; m1 = m1n;
        }
        float e0 = fexp2(d0 - m0);
        float e1 = fexp2(d1 - m1);
        s0 += e0; s1 += e1;
        a00 = fmaf(e0, g[7].x, a00); a01 = fmaf(e0, g[7].y, a01); a02 = fmaf(e0, g[7].z, a02);
        a10 = fmaf(e1, g[7].x, a10); a11 = fmaf(e1, g[7].y, a11); a12 = fmaf(e1, g[7].z, a12);
    }

    const int o = split * NPX;   // partials laid out [split][pixel] (coalesced)
    pm[o + px0] = m0; ps[o + px0] = s0; pc0[o + px0] = a00; pc1[o + px0] = a01; pc2[o + px0] = a02;
    pm[o + px1] = m1; ps[o + px1] = s1; pc0[o + px1] = a10; pc1[o + px1] = a11; pc2[o + px1] = a12;
}

// ---------------- combine partials + write output ----------------
__global__ void combine(const float* __restrict__ x, const float* __restrict__ t,
                        const float* __restrict__ pm, const float* __restrict__ ps,
                        const float* __restrict__ pc0, const float* __restrict__ pc1,
                        const float* __restrict__ pc2, float* __restrict__ out) {
    int px = blockIdx.x * blockDim.x + threadIdx.x;
    if (px >= NPX) return;
    float M = -1e30f, S = 0.0f, C0 = 0.0f, C1 = 0.0f, C2 = 0.0f;
#pragma unroll 4
    for (int sp = 0; sp < SPLITS; sp++) {
        int o = sp * NPX + px;
        float mi = pm[o];
        float Mn = fmaxf(M, mi);
        float al = fexp2(M - Mn);
        float be = fexp2(mi - Mn);
        S = S * al + ps[o] * be;
        C0 = C0 * al + pc0[o] * be;
        C1 = C1 * al + pc1[o] * be;
        C2 = C2 * al + pc2[o] * be;
        M = Mn;
    }
    float bt2 = t[0];
    float at = sqrtf(1.0f - bt2);
    float invS = 1.0f / S;
    float ibt = 1.0f / bt2;
    int b = px >> 10, rem = px & 1023, h = rem >> 5, w = rem & 31;
    int xi = b * 3072 + h * 32 + w;
    out[xi]        = (at * C0 * invS - x[xi]) * ibt;
    out[xi + 1024] = (at * C1 * invS - x[xi + 1024]) * ibt;
    out[xi + 2048] = (at * C2 * invS - x[xi + 2048]) * ibt;
}

extern "C" void kernel_launch(void* const* d_in, const int* in_sizes, int n_in,
                              void* d_out, int out_size, void* d_ws, size_t ws_size,
                              hipStream_t stream) {
    const float* x = (const float*)d_in[0];
    const float* patches = (const float*)d_in[1];
    const float* t = (const float*)d_in[2];
    float* out = (float*)d_out;
    float* ws = (float*)d_ws;

    float* rec  = ws;                       // 8192*32   = 262144 floats
    float* xcol = ws + 262144;              // 8192*28   = 229376 floats
    float* pm   = ws + 491520;              // 64*8192 each
    float* ps   = pm + SPLITS * NPX;
    float* pc0  = ps + SPLITS * NPX;
    float* pc1  = pc0 + SPLITS * NPX;
    float* pc2  = pc1 + SPLITS * NPX;

    hipLaunchKernelGGL(prep_patches, dim3(NPATCH / 256), dim3(256), 0, stream, patches, t, rec);
    hipLaunchKernelGGL(im2col, dim3((NPX * XREC) / 256), dim3(256), 0, stream, x, xcol);
    hipLaunchKernelGGL(main_kernel, dim3(SPLITS, TILES), dim3(256), 0, stream,
                       rec, xcol, pm, ps, pc0, pc1, pc2);
    hipLaunchKernelGGL(combine, dim3(NPX / 256), dim3(256), 0, stream,
                       x, t, pm, ps, pc0, pc1, pc2, out);
}

// Round 2
// 40.922 us; speedup vs baseline: 2.1927x; 2.1927x over previous
//
#include <hip/hip_runtime.h>
#include <math.h>

typedef __attribute__((ext_vector_type(8))) short short8;
typedef __attribute__((ext_vector_type(4))) float f32x4;

#define NPX 8192
#define NPATCH 8192
#define SPLITS 8
#define PXBLOCKS 64          // 128 px per block (8 waves x 16 px)
#define TILES_PER_SPLIT 64   // 8192 patches / 16 / 8 splits
#define CHUNK_TILES 16
#define NCHUNKS 4

__device__ __forceinline__ float fexp2(float x) {
#if __has_builtin(__builtin_amdgcn_exp2f)
    return __builtin_amdgcn_exp2f(x);
#else
    return exp2f(x);
#endif
}

__device__ __forceinline__ unsigned short f2bf(float f) {
    unsigned u = __float_as_uint(f);
    u = u + 0x7FFFu + ((u >> 16) & 1u);
    return (unsigned short)(u >> 16);
}
__device__ __forceinline__ float bf2f(unsigned short h) {
    return __uint_as_float(((unsigned)h) << 16);
}

// ---- prep: build MFMA fragment-ordered hi/lo bf16 records for patches & pixels
// A-side (patches): record[j*64 + kchunk*16 + (p&15)] = 8 bf16 of scaled patch,
//   K-slot 27 carries B2 (hi/lo split), slots 28..31 zero.
// B-side (pixels):  record[w*64 + kchunk*16 + (px&15)] = 8 bf16 of x-neighborhood,
//   K-slot 27 = 1.0.
__global__ void __launch_bounds__(256) prep(const float* __restrict__ x,
                          const float* __restrict__ patches,
                          const float* __restrict__ t,
                          float* __restrict__ gAh, float* __restrict__ gAl,
                          float* __restrict__ gBh, float* __restrict__ gBl,
                          float* __restrict__ gCent) {
    int id = blockIdx.x * 256 + threadIdx.x;
    float bt2 = t[0];
    float at = sqrtf(1.0f - bt2);
    const float L2E = 1.4426950408889634f;
    if (id < NPATCH) {
        int p = id;
        const float* src = patches + p * 27;
        float v[27]; float pn = 0.f;
#pragma unroll
        for (int k = 0; k < 27; k++) { v[k] = src[k]; pn += v[k] * v[k]; }
        float A2 = at * L2E / bt2;                       // logit slope, log2 units
        float B2 = -at * at * pn * L2E / (2.0f * bt2);   // bias, log2 units
        float sv[28];
#pragma unroll
        for (int k = 0; k < 27; k++) sv[k] = A2 * v[k];
        sv[27] = B2;
        int j = p >> 4, pi = p & 15;
        short8* Ah8 = (short8*)gAh; short8* Al8 = (short8*)gAl;
#pragma unroll
        for (int c = 0; c < 4; c++) {
            short8 H, L;
#pragma unroll
            for (int i = 0; i < 8; i++) {
                int k = c * 8 + i;
                unsigned short hb = 0, lb = 0;
                if (k < 28) { hb = f2bf(sv[k]); lb = f2bf(sv[k] - bf2f(hb)); }
                H[i] = (short)hb; L[i] = (short)lb;
            }
            Ah8[j * 64 + c * 16 + pi] = H;
            Al8[j * 64 + c * 16 + pi] = L;
        }
        gCent[j * 48 + 0  + pi] = v[4];    // center c=0
        gCent[j * 48 + 16 + pi] = v[13];   // center c=1
        gCent[j * 48 + 32 + pi] = v[22];   // center c=2
    } else {
        int px = id - NPATCH;
        int b = px >> 10, rem = px & 1023, h = rem >> 5, w = rem & 31;
        float xv[28];
#pragma unroll
        for (int c3 = 0; c3 < 3; c3++)
#pragma unroll
        for (int dr = 0; dr < 3; dr++)
#pragma unroll
        for (int dc = 0; dc < 3; dc++) {
            int hh = h + dr - 1, ww = w + dc - 1;
            float val = 0.f;
            if ((unsigned)hh < 32u && (unsigned)ww < 32u)
                val = x[b * 3072 + c3 * 1024 + hh * 32 + ww];
            xv[c3 * 9 + dr * 3 + dc] = val;
        }
        xv[27] = 1.0f;
        int wv = px >> 4, pi = px & 15;
        short8* Bh8 = (short8*)gBh; short8* Bl8 = (short8*)gBl;
#pragma unroll
        for (int c = 0; c < 4; c++) {
            short8 H, L;
#pragma unroll
            for (int i = 0; i < 8; i++) {
                int k = c * 8 + i;
                unsigned short hb = 0, lb = 0;
                if (k < 28) { hb = f2bf(xv[k]); lb = f2bf(xv[k] - bf2f(hb)); }
                H[i] = (short)hb; L[i] = (short)lb;
            }
            Bh8[wv * 64 + c * 16 + pi] = H;
            Bl8[wv * 64 + c * 16 + pi] = L;
        }
    }
}

// ---- main: MFMA logits + online softmax + center accumulation
__global__ void __launch_bounds__(512) main_mfma(
        const float* __restrict__ gAh, const float* __restrict__ gAl,
        const float* __restrict__ gBh, const float* __restrict__ gBl,
        const float* __restrict__ gCent,
        float* __restrict__ pm, float* __restrict__ ps,
        float* __restrict__ pc0, float* __restrict__ pc1, float* __restrict__ pc2) {
    __shared__ short8 sAh[CHUNK_TILES * 64];   // 16 KB
    __shared__ short8 sAl[CHUNK_TILES * 64];   // 16 KB
    __shared__ float  sCent[CHUNK_TILES * 48]; // 3 KB
    const int tid = threadIdx.x;
    const int lane = tid & 63, wid = tid >> 6;
    const int split = blockIdx.x, pxb = blockIdx.y;
    const int wglob = pxb * 8 + wid;           // global wave id = pixel group
    const int g = lane >> 4;

    // loop-invariant pixel fragments (hi, lo)
    short8 bh = ((const short8*)gBh)[wglob * 64 + lane];
    short8 bl = ((const short8*)gBl)[wglob * 64 + lane];

    float m = -1e30f, s = 0.f, a0 = 0.f, a1 = 0.f, a2 = 0.f;

    for (int chunk = 0; chunk < NCHUNKS; chunk++) {
        const int tb = split * TILES_PER_SPLIT + chunk * CHUNK_TILES;
        __syncthreads();
        {
            const float4* srcA = (const float4*)gAh + tb * 64;
            const float4* srcL = (const float4*)gAl + tb * 64;
            float4* dA = (float4*)sAh; float4* dL = (float4*)sAl;
            dA[tid] = srcA[tid]; dA[tid + 512] = srcA[tid + 512];
            dL[tid] = srcL[tid]; dL[tid + 512] = srcL[tid + 512];
            if (tid < 192) ((float4*)sCent)[tid] = ((const float4*)gCent)[tb * 12 + tid];
        }
        __syncthreads();
        for (int tt = 0; tt < CHUNK_TILES; tt++) {
            short8 ah = sAh[tt * 64 + lane];
            short8 al = sAl[tt * 64 + lane];
            f32x4 d = {0.f, 0.f, 0.f, 0.f};
            d = __builtin_amdgcn_mfma_f32_16x16x32_bf16(ah, bh, d, 0, 0, 0);
            d = __builtin_amdgcn_mfma_f32_16x16x32_bf16(ah, bl, d, 0, 0, 0);
            d = __builtin_amdgcn_mfma_f32_16x16x32_bf16(al, bh, d, 0, 0, 0);
            // lane holds logits for patches tbase + g*4 + {0..3}, pixel = lane&15
            float tmax = fmaxf(fmaxf(d.x, d.y), fmaxf(d.z, d.w));
            if (__any(tmax > m - 30.0f)) {         // contribution > 2^-30?
                if (__any(tmax > m + 8.0f)) {      // defer-max rescale
                    float mn = fmaxf(m, tmax);
                    float sc = fexp2(m - mn);
                    s *= sc; a0 *= sc; a1 *= sc; a2 *= sc; m = mn;
                }
                float e0 = fexp2(d.x - m), e1 = fexp2(d.y - m);
                float e2 = fexp2(d.z - m), e3 = fexp2(d.w - m);
                s += (e0 + e1) + (e2 + e3);
                const float4 c0 = ((const float4*)sCent)[tt * 12 + 0 + g];
                const float4 c1 = ((const float4*)sCent)[tt * 12 + 4 + g];
                const float4 c2 = ((const float4*)sCent)[tt * 12 + 8 + g];
                a0 = fmaf(e0, c0.x, fmaf(e1, c0.y, fmaf(e2, c0.z, fmaf(e3, c0.w, a0))));
                a1 = fmaf(e0, c1.x, fmaf(e1, c1.y, fmaf(e2, c1.z, fmaf(e3, c1.w, a1))));
                a2 = fmaf(e0, c2.x, fmaf(e1, c2.y, fmaf(e2, c2.z, fmaf(e3, c2.w, a2))));
            }
        }
    }
    // merge the 4 lane-groups that share pixel (lane&15)
#pragma unroll
    for (int off = 16; off <= 32; off <<= 1) {
        float mo = __shfl_xor(m, off);
        float so = __shfl_xor(s, off);
        float b0 = __shfl_xor(a0, off);
        float b1 = __shfl_xor(a1, off);
        float b2 = __shfl_xor(a2, off);
        float mn = fmaxf(m, mo);
        float w1 = fexp2(m - mn), w2 = fexp2(mo - mn);
        s  = s  * w1 + so * w2;
        a0 = a0 * w1 + b0 * w2;
        a1 = a1 * w1 + b1 * w2;
        a2 = a2 * w1 + b2 * w2;
        m = mn;
    }
    if (lane < 16) {
        int px = wglob * 16 + lane;
        int o = split * NPX + px;
        pm[o] = m; ps[o] = s; pc0[o] = a0; pc1[o] = a1; pc2[o] = a2;
    }
}

// ---- combine partials + write output ----
__global__ void __launch_bounds__(256) combine(const float* __restrict__ x, const float* __restrict__ t,
                        const float* __restrict__ pm, const float* __restrict__ ps,
                        const float* __restrict__ pc0, const float* __restrict__ pc1,
                        const float* __restrict__ pc2, float* __restrict__ out) {
    int px = blockIdx.x * blockDim.x + threadIdx.x;
    if (px >= NPX) return;
    float M = -1e30f, S = 0.0f, C0 = 0.0f, C1 = 0.0f, C2 = 0.0f;
#pragma unroll
    for (int sp = 0; sp < SPLITS; sp++) {
        int o = sp * NPX + px;
        float mi = pm[o];
        float Mn = fmaxf(M, mi);
        float al = fexp2(M - Mn);
        float be = fexp2(mi - Mn);
        S  = S  * al + ps[o]  * be;
        C0 = C0 * al + pc0[o] * be;
        C1 = C1 * al + pc1[o] * be;
        C2 = C2 * al + pc2[o] * be;
        M = Mn;
    }
    float bt2 = t[0];
    float at = sqrtf(1.0f - bt2);
    float invS = 1.0f / S;
    float ibt = 1.0f / bt2;
    int b = px >> 10, rem = px & 1023, h = rem >> 5, w = rem & 31;
    int xi = b * 3072 + h * 32 + w;
    out[xi]        = (at * C0 * invS - x[xi]) * ibt;
    out[xi + 1024] = (at * C1 * invS - x[xi + 1024]) * ibt;
    out[xi + 2048] = (at * C2 * invS - x[xi + 2048]) * ibt;
}

extern "C" void kernel_launch(void* const* d_in, const int* in_sizes, int n_in,
                              void* d_out, int out_size, void* d_ws, size_t ws_size,
                              hipStream_t stream) {
    const float* x = (const float*)d_in[0];
    const float* patches = (const float*)d_in[1];
    const float* t = (const float*)d_in[2];
    float* out = (float*)d_out;
    float* ws = (float*)d_ws;

    float* gAh   = ws;                    // 512*64*4  = 131072 floats
    float* gAl   = ws + 131072;
    float* gBh   = ws + 262144;
    float* gBl   = ws + 393216;
    float* gCent = ws + 524288;           // 512*48    = 24576 floats
    float* pm    = ws + 548864;           // 8*8192 each
    float* ps    = pm + SPLITS * NPX;
    float* pc0   = ps + SPLITS * NPX;
    float* pc1   = pc0 + SPLITS * NPX;
    float* pc2   = pc1 + SPLITS * NPX;

    hipLaunchKernelGGL(prep, dim3(64), dim3(256), 0, stream,
                       x, patches, t, gAh, gAl, gBh, gBl, gCent);
    hipLaunchKernelGGL(main_mfma, dim3(SPLITS, PXBLOCKS), dim3(512), 0, stream,
                       gAh, gAl, gBh, gBl, gCent, pm, ps, pc0, pc1, pc2);
    hipLaunchKernelGGL(combine, dim3(NPX / 256), dim3(256), 0, stream,
                       x, t, pm, ps, pc0, pc1, pc2, out);
}